// Round 11
// baseline (499.611 us; speedup 1.0000x reference)
//
#include <hip/hip_runtime.h>
#include <math.h>

#define NB   8
#define NC   256
#define ND   64
#define NPIX 4096

typedef short bf16x8 __attribute__((ext_vector_type(8)));   // 8 bf16 (4 VGPRs)
typedef float f32x4  __attribute__((ext_vector_type(4)));
typedef float f32x16 __attribute__((ext_vector_type(16)));

static __device__ __forceinline__ ushort f2bf(float f) {
    uint u = __float_as_uint(f);
    u += 0x7fffu + ((u >> 16) & 1u);      // round-to-nearest-even
    return (ushort)(u >> 16);
}
static __device__ __forceinline__ float bf2f(ushort h) {
    return __uint_as_float(((uint)h) << 16);
}

// ---------------------------------------------------------------------------
// prep_k: transpose_w (ids 0..383) + transpose_x (ids 384..2431) fused
// (R9-proven). transpose_x XCD-pinned by batch (b = xid&7), R10-proven.
// Shared LDS 17408 B.
// ---------------------------------------------------------------------------
__global__ __launch_bounds__(256) void prep_k(
    const float* __restrict__ x,
    const float* __restrict__ Wq, const float* __restrict__ Wk,
    const float* __restrict__ Wv,
    ushort* __restrict__ xth, ushort* __restrict__ xtl,
    ushort* __restrict__ qh, ushort* __restrict__ ql,
    ushort* __restrict__ kh, ushort* __restrict__ kl,
    ushort* __restrict__ vh)
{
    __shared__ char shbuf[64 * 68 * 4];
    const int id = blockIdx.x;
    const int t = threadIdx.x;

    if (id < 384) {
        // ---- transpose_w body (g = id) ----
        float* wb = (float*)shbuf;
        const int g = id;
        const float* src;
        ushort *dh, *dl;
        int co, Co, split;
        if (g < 64)       { src = Wq + (size_t)g * 2304; co = g;       Co = 64;  dh = qh; dl = ql; split = 1; }
        else if (g < 128) { src = Wk + (size_t)(g - 64) * 2304; co = g - 64; Co = 64; dh = kh; dl = kl; split = 1; }
        else              { src = Wv + (size_t)(g - 128) * 2304; co = g - 128; Co = 256; dh = vh; dl = nullptr; split = 0; }

        for (int i = t; i < 2304; i += 256) wb[i] = src[i];
        __syncthreads();
        for (int j = t; j < 2304; j += 256) {
            const int rs = j >> 8, ci = j & 255;
            const float v = wb[ci * 9 + rs];
            const ushort hv = f2bf(v);
            const size_t o = ((size_t)(rs * Co + co)) * 256 + ci;
            dh[o] = hv;
            if (split) dl[o] = f2bf(v - bf2f(hv));
        }
    } else {
        // ---- transpose_x body, XCD-pinned: b = xid&7 ----
        float (*tile)[68] = (float(*)[68])shbuf;
        const int xid = id - 384;
        const int b = xid & 7;
        const int p0 = ((xid >> 3) & 63) * 64;
        const int c0 = (xid >> 9) * 64;

        const int cl = t >> 4, p4 = (t & 15) * 4;
        #pragma unroll
        for (int i = 0; i < 4; i++) {
            const int c = cl + 16 * i;
            *(float4*)&tile[c][p4] =
                *(const float4*)&x[((size_t)(b * NC + c0 + c)) * NPIX + p0 + p4];
        }
        __syncthreads();

        const int pl = t & 63, ch = t >> 6;
        float v[16];
        #pragma unroll
        for (int j = 0; j < 16; j++) v[j] = tile[ch * 16 + j][pl];
        ushort h[16], l[16];
        #pragma unroll
        for (int j = 0; j < 16; j++) {
            h[j] = f2bf(v[j]);
            l[j] = f2bf(v[j] - bf2f(h[j]));
        }
        const size_t o = ((size_t)(b * NPIX + p0 + pl)) * 256 + c0 + ch * 16;
        *(uint4*)&xth[o]     = *(uint4*)&h[0];
        *(uint4*)&xth[o + 8] = *(uint4*)&h[8];
        *(uint4*)&xtl[o]     = *(uint4*)&l[0];
        *(uint4*)&xtl[o + 8] = *(uint4*)&l[8];
    }
}

// ---------------------------------------------------------------------------
// MFMA conv (q/k, split-bf16 3-term) v4: W DIRECT-TO-REGISTER.
// The old wsp LDS staging is redundant: the A-frag read pattern
// wsp[rs*1536 + l31*24 + khl*8] is wave-id-independent and maps to the clean
// global address wth[(rs*64+l31)*256 + ci0 + khl*8] (A1: +8192). Loading W
// frags global->reg at chunk-top deletes 2304 uint4/chunk of LDS round trip,
// all wsp ds_reads, and 2 of 4 barriers; pass0+pass1 run back-to-back in one
// 108-MFMA interval. Per-accumulator MFMA order IDENTICAL to R0 (pass0 loop
// then pass1 loop; B frags re-read from x-LDS in pass1) -> bit-identical.
// W regs 144 + acc 64: fine at 1 block/CU (grid 256, b=id&7 XCD pin,
// launch_bounds(256,1) -> ~512-reg budget). dyn LDS 38272 B.
// ---------------------------------------------------------------------------
__global__ __launch_bounds__(256, 1) void conv_split_k(
    const ushort* __restrict__ xth, const ushort* __restrict__ xtl,
    const ushort* __restrict__ wqh, const ushort* __restrict__ wql,
    const ushort* __restrict__ wkh, const ushort* __restrict__ wkl,
    const float* __restrict__ bq, const float* __restrict__ bk,
    ushort* __restrict__ qoh, ushort* __restrict__ qol,
    ushort* __restrict__ koh, ushort* __restrict__ kol)
{
    extern __shared__ char smem[];
    ushort* xsh = (ushort*)smem;                 // [6][66][24]
    ushort* xsl = xsh + 6 * 66 * 24;             // [6][66][24]
    float*  sbias = (float*)(xsl + 6 * 66 * 24); // [64]

    const int id = blockIdx.x;
    const int b = id & 7, hq = (id >> 3) & 15, ct = id >> 7;
    const ushort* wth = ct ? wkh : wqh;
    const ushort* wtl = ct ? wkl : wql;
    const float*  bias = ct ? bk : bq;
    ushort* outh = ct ? koh : qoh;
    ushort* outl = ct ? kol : qol;

    const int t = threadIdx.x;
    const int wv = t >> 6, lane = t & 63;
    const int l31 = lane & 31, khl = lane >> 5;
    const int lanebase = l31 * 24 + khl * 8;
    const int h = hq * 4 + wv;

    if (t < 64) sbias[t] = bias[t];
    for (int i = t; i < 384; i += 256) {
        const int p = i / 192, r2 = i % 192;
        const int row = r2 / 32, e = (r2 % 32) / 16, ci = r2 & 15;
        (p ? xsl : xsh)[(row * 66 + e * 65) * 24 + ci] = 0;
    }

    // per-lane W base (elements): co=l31, ci-sub=khl*8
    const size_t wbase = (size_t)l31 * 256 + khl * 8;

    f32x16 a00 = {0}, a01 = {0}, a10 = {0}, a11 = {0};  // [ms(co)][ns(pix)]

    for (int ch = 0; ch < 16; ch++) {
        const int ci0 = ch * 16;

        // W frags for this chunk: global->reg, issued before the barrier so
        // L2 latency hides under barrier + x-stage. Values identical to the
        // old wsp reads (derivation in header comment).
        bf16x8 whA0[9], whA1[9], wlA0[9], wlA1[9];
        #pragma unroll
        for (int rs = 0; rs < 9; rs++) {
            const size_t o = (size_t)rs * 16384 + wbase + ci0;
            whA0[rs] = *(const bf16x8*)&wth[o];
            whA1[rs] = *(const bf16x8*)&wth[o + 8192];
            wlA0[rs] = *(const bf16x8*)&wtl[o];
            wlA1[rs] = *(const bf16x8*)&wtl[o + 8192];
        }

        __syncthreads();   // prev chunk's x-LDS reads done
        #pragma unroll
        for (int pl2 = 0; pl2 < 2; pl2++) {
            const ushort* src = pl2 ? xtl : xth;
            ushort* dst = pl2 ? xsl : xsh;
            #pragma unroll
            for (int i = 0; i < 3; i++) {
                const int a = i * 256 + t;
                const int cih = a & 1, col = (a >> 1) & 63, row = a >> 7;
                const int hs = hq * 4 + row - 1;
                uint4 val = {0, 0, 0, 0};
                if (hs >= 0 && hs < 64)
                    val = *(const uint4*)&src[((size_t)(b * NPIX + hs * 64 + col)) * 256 + ci0 + cih * 8];
                *(uint4*)&dst[(row * 66 + 1 + col) * 24 + cih * 8] = val;
            }
        }
        __syncthreads();

        // pass0: (wh.xh) + (wh.xl) — per-acc order identical to R0
        #pragma unroll
        for (int rs = 0; rs < 9; rs++) {
            const int r = rs / 3, s = rs % 3;
            const int xo = ((wv + r) * 66 + s) * 24 + lanebase;
            bf16x8 B0h = *(const bf16x8*)&xsh[xo];
            bf16x8 B1h = *(const bf16x8*)&xsh[xo + 768];
            bf16x8 B0l = *(const bf16x8*)&xsl[xo];
            bf16x8 B1l = *(const bf16x8*)&xsl[xo + 768];
            a00 = __builtin_amdgcn_mfma_f32_32x32x16_bf16(whA0[rs], B0h, a00, 0, 0, 0);
            a01 = __builtin_amdgcn_mfma_f32_32x32x16_bf16(whA0[rs], B1h, a01, 0, 0, 0);
            a10 = __builtin_amdgcn_mfma_f32_32x32x16_bf16(whA1[rs], B0h, a10, 0, 0, 0);
            a11 = __builtin_amdgcn_mfma_f32_32x32x16_bf16(whA1[rs], B1h, a11, 0, 0, 0);
            a00 = __builtin_amdgcn_mfma_f32_32x32x16_bf16(whA0[rs], B0l, a00, 0, 0, 0);
            a01 = __builtin_amdgcn_mfma_f32_32x32x16_bf16(whA0[rs], B1l, a01, 0, 0, 0);
            a10 = __builtin_amdgcn_mfma_f32_32x32x16_bf16(whA1[rs], B0l, a10, 0, 0, 0);
            a11 = __builtin_amdgcn_mfma_f32_32x32x16_bf16(whA1[rs], B1l, a11, 0, 0, 0);
        }
        // pass1: (wl.xh) — same interval, x-LDS only read (no barrier needed)
        #pragma unroll
        for (int rs = 0; rs < 9; rs++) {
            const int r = rs / 3, s = rs % 3;
            const int xo = ((wv + r) * 66 + s) * 24 + lanebase;
            bf16x8 B0h = *(const bf16x8*)&xsh[xo];
            bf16x8 B1h = *(const bf16x8*)&xsh[xo + 768];
            a00 = __builtin_amdgcn_mfma_f32_32x32x16_bf16(wlA0[rs], B0h, a00, 0, 0, 0);
            a01 = __builtin_amdgcn_mfma_f32_32x32x16_bf16(wlA0[rs], B1h, a01, 0, 0, 0);
            a10 = __builtin_amdgcn_mfma_f32_32x32x16_bf16(wlA1[rs], B0h, a10, 0, 0, 0);
            a11 = __builtin_amdgcn_mfma_f32_32x32x16_bf16(wlA1[rs], B1h, a11, 0, 0, 0);
        }
    }

    const float4* sb4 = (const float4*)sbias;
    #pragma unroll
    for (int ms = 0; ms < 2; ms++)
        #pragma unroll
        for (int ns = 0; ns < 2; ns++) {
            const f32x16 av = ms ? (ns ? a11 : a10) : (ns ? a01 : a00);
            const int p = h * 64 + ns * 32 + l31;
            #pragma unroll
            for (int g = 0; g < 4; g++) {
                const float4 bi = sb4[ms * 8 + 2 * g + khl];
                float v0 = av[4 * g + 0] + bi.x;
                float v1 = av[4 * g + 1] + bi.y;
                float v2 = av[4 * g + 2] + bi.z;
                float v3 = av[4 * g + 3] + bi.w;
                ushort4 hv, lv;
                hv.x = f2bf(v0); lv.x = f2bf(v0 - bf2f(hv.x));
                hv.y = f2bf(v1); lv.y = f2bf(v1 - bf2f(hv.y));
                hv.z = f2bf(v2); lv.z = f2bf(v2 - bf2f(hv.z));
                hv.w = f2bf(v3); lv.w = f2bf(v3 - bf2f(hv.w));
                const size_t o = ((size_t)(b * NPIX + p)) * 64 + ms * 32 + 8 * g + 4 * khl;
                *(ushort4*)&outh[o] = hv;
                *(ushort4*)&outl[o] = lv;
            }
        }
}

// ---------------------------------------------------------------------------
// MFMA conv (v, plain bf16) v4: W direct-to-register (same derivation:
// B0 = wtv[(rs*256+co0+l31)*256 + ci0 + khl*8], B1 = +8192). Deletes wsp
// LDS round trip; 2 barriers/chunk. W regs 72 + acc 64 fits (256,2).
// grid 512 1-D (b=id&7 XCD pin), 2 blocks/CU. dyn LDS 19264 B.
// ---------------------------------------------------------------------------
__global__ __launch_bounds__(256, 2) void conv_v_k(
    const ushort* __restrict__ xth, const ushort* __restrict__ wtv,
    const float* __restrict__ bv, ushort* __restrict__ vout)
{
    extern __shared__ char smem[];
    ushort* xsh = (ushort*)smem;                 // [6][66][24]
    float*  sbias = (float*)(xsh + 6 * 66 * 24); // [64]

    const int id = blockIdx.x;
    const int b = id & 7, hq = (id >> 3) & 15, co0 = (id >> 7) * 64;
    const int t = threadIdx.x;
    const int wv = t >> 6, lane = t & 63;
    const int l31 = lane & 31, khl = lane >> 5;
    const int lanebase = l31 * 24 + khl * 8;
    const int h = hq * 4 + wv;

    if (t < 64) sbias[t] = bv[co0 + t];
    for (int i = t; i < 192; i += 256) {
        const int row = i / 32, e = (i % 32) / 16, ci = i & 15;
        xsh[(row * 66 + e * 65) * 24 + ci] = 0;
    }

    const size_t wbase = (size_t)(co0 + l31) * 256 + khl * 8;

    f32x16 a00 = {0}, a01 = {0}, a10 = {0}, a11 = {0};  // [ms(pix)][ns(co)]

    for (int ch = 0; ch < 16; ch++) {
        const int ci0 = ch * 16;

        bf16x8 wB0[9], wB1[9];
        #pragma unroll
        for (int rs = 0; rs < 9; rs++) {
            const size_t o = (size_t)rs * 65536 + wbase + ci0;
            wB0[rs] = *(const bf16x8*)&wtv[o];
            wB1[rs] = *(const bf16x8*)&wtv[o + 8192];
        }

        __syncthreads();
        #pragma unroll
        for (int i = 0; i < 3; i++) {
            const int a = i * 256 + t;
            const int cih = a & 1, col = (a >> 1) & 63, row = a >> 7;
            const int hs = hq * 4 + row - 1;
            uint4 val = {0, 0, 0, 0};
            if (hs >= 0 && hs < 64)
                val = *(const uint4*)&xth[((size_t)(b * NPIX + hs * 64 + col)) * 256 + ci0 + cih * 8];
            *(uint4*)&xsh[(row * 66 + 1 + col) * 24 + cih * 8] = val;
        }
        __syncthreads();

        #pragma unroll
        for (int rs = 0; rs < 9; rs++) {
            const int r = rs / 3, s = rs % 3;
            const int xo = ((wv + r) * 66 + s) * 24 + lanebase;
            bf16x8 A0 = *(const bf16x8*)&xsh[xo];
            bf16x8 A1 = *(const bf16x8*)&xsh[xo + 768];
            a00 = __builtin_amdgcn_mfma_f32_32x32x16_bf16(A0, wB0[rs], a00, 0, 0, 0);
            a01 = __builtin_amdgcn_mfma_f32_32x32x16_bf16(A0, wB1[rs], a01, 0, 0, 0);
            a10 = __builtin_amdgcn_mfma_f32_32x32x16_bf16(A1, wB0[rs], a10, 0, 0, 0);
            a11 = __builtin_amdgcn_mfma_f32_32x32x16_bf16(A1, wB1[rs], a11, 0, 0, 0);
        }
    }

    #pragma unroll
    for (int ns = 0; ns < 2; ns++) {
        const int co = co0 + ns * 32 + l31;
        const float bi = sbias[ns * 32 + l31];
        #pragma unroll
        for (int ms = 0; ms < 2; ms++) {
            const f32x16 av = ms ? (ns ? a11 : a10) : (ns ? a01 : a00);
            #pragma unroll
            for (int g = 0; g < 4; g++) {
                const int p = h * 64 + ms * 32 + 8 * g + 4 * khl;
                ushort4 ov;
                ov.x = f2bf(av[4 * g + 0] + bi);
                ov.y = f2bf(av[4 * g + 1] + bi);
                ov.z = f2bf(av[4 * g + 2] + bi);
                ov.w = f2bf(av[4 * g + 3] + bi);
                *(ushort4*)&vout[((size_t)(b * NC + co)) * NPIX + p] = ov;
            }
        }
    }
}

// ---------------------------------------------------------------------------
// MFMA flash attention v7 (R3/R9/R10, session best): pipeline-skewed, ONE
// lgkm-only barrier per iter, K/V register prefetch, P buffer 128B rows +
// XOR swizzle byte^=(row&7)<<4 both sides. Bit-identical numerics to v4.
// grid 512 1-D (b = id&7 -> XCD pin), block 256, LDS ~17.7 KB.
// ---------------------------------------------------------------------------
__global__ __launch_bounds__(256, 2) void attn_k(
    const ushort* __restrict__ qh, const ushort* __restrict__ ql,
    const ushort* __restrict__ kh, const ushort* __restrict__ kl,
    const ushort* __restrict__ vb, const float* __restrict__ x,
    float* __restrict__ out)
{
    const int id = blockIdx.x;
    const int b  = id & 7;
    const int m0 = (id >> 3) * 64;
    const int t  = threadIdx.x;
    const int w  = t >> 6;
    const int lane = t & 63;
    const int quad = lane >> 4;
    const int l16  = lane & 15;

    __shared__ ushort sps[2][64 * 64];   // P double buffer, 128B rows, swizzled
    __shared__ float  red[4][64];
    __shared__ float  ivl[64];

    // hoisted Q B-frags: B[col=m=l16][k=d]
    bf16x8 aqh[4][2], aql[4][2];
    #pragma unroll
    for (int mg = 0; mg < 4; mg++)
        #pragma unroll
        for (int ks = 0; ks < 2; ks++) {
            const size_t g = ((size_t)b * NPIX + m0 + mg * 16 + l16) * ND + ks * 32 + quad * 8;
            aqh[mg][ks] = *(const bf16x8*)&qh[g];
            aql[mg][ks] = *(const bf16x8*)&ql[g];
        }

    // per-wave base offsets
    const size_t kbase = ((size_t)b * NPIX + 16 * w + l16) * ND + quad * 8;   // + n0*ND + ks*32
    size_t vbase[4];
    #pragma unroll
    for (int ct = 0; ct < 4; ct++)
        vbase[ct] = ((size_t)b * NC + 64 * w + ct * 16 + l16) * NPIX + quad * 8;  // + n0 + ks*32

    // preload K/V frags for n0 = 0
    bf16x8 kfh[2], kfl[2], vf[4][2];
    #pragma unroll
    for (int ks = 0; ks < 2; ks++) {
        kfh[ks] = *(const bf16x8*)&kh[kbase + ks * 32];
        kfl[ks] = *(const bf16x8*)&kl[kbase + ks * 32];
    }
    #pragma unroll
    for (int ct = 0; ct < 4; ct++)
        #pragma unroll
        for (int ks = 0; ks < 2; ks++)
            vf[ct][ks] = *(const bf16x8*)&vb[vbase[ct] + ks * 32];

    f32x4 acc[4][4];
    #pragma unroll
    for (int i = 0; i < 4; i++)
        #pragma unroll
        for (int j = 0; j < 4; j++) acc[i][j] = (f32x4){0.f, 0.f, 0.f, 0.f};
    float lsum[4] = {0.f, 0.f, 0.f, 0.f};

    // QK tile: S^T = K.Q^T (kf regs hold this tile's K), exp, pack -> sps[obuf]
    auto qk_tile = [&](int obuf) {
        #pragma unroll
        for (int mg = 0; mg < 4; mg++) {
            f32x4 s = {0.f, 0.f, 0.f, 0.f};
            #pragma unroll
            for (int ks = 0; ks < 2; ks++) {
                s = __builtin_amdgcn_mfma_f32_16x16x32_bf16(kfh[ks], aqh[mg][ks], s, 0, 0, 0);
                s = __builtin_amdgcn_mfma_f32_16x16x32_bf16(kfl[ks], aqh[mg][ks], s, 0, 0, 0);
                s = __builtin_amdgcn_mfma_f32_16x16x32_bf16(kfh[ks], aql[mg][ks], s, 0, 0, 0);
            }
            const ushort p0 = f2bf(__expf(s[0] - 30.f));
            const ushort p1 = f2bf(__expf(s[1] - 30.f));
            const ushort p2 = f2bf(__expf(s[2] - 30.f));
            const ushort p3 = f2bf(__expf(s[3] - 30.f));
            lsum[mg] += (bf2f(p0) + bf2f(p1)) + (bf2f(p2) + bf2f(p3));
            uint2 pk;
            pk.x = (uint)p0 | ((uint)p1 << 16);
            pk.y = (uint)p2 | ((uint)p3 << 16);
            const int row = mg * 16 + l16;
            const int bo = (32 * w + quad * 8) ^ ((row & 7) << 4);
            *(uint2*)((char*)&sps[obuf][0] + row * 128 + bo) = pk;
        }
    };

    // prologue: QK(0) -> sps[0]; prefetch K(64); barrier
    qk_tile(0);
    {
        const size_t kb = kbase + (size_t)64 * ND;
        #pragma unroll
        for (int ks = 0; ks < 2; ks++) {
            kfh[ks] = *(const bf16x8*)&kh[kb + ks * 32];
            kfl[ks] = *(const bf16x8*)&kl[kb + ks * 32];
        }
    }
    asm volatile("s_waitcnt lgkmcnt(0)\n\ts_barrier" ::: "memory");

    for (int n0 = 0; n0 < NPIX; n0 += 64) {
        const int buf = (n0 >> 6) & 1;
        const bool nxt = (n0 + 64) < NPIX;

        // issue P reads for PV(n0) first (latency hides under QK MFMAs)
        bf16x8 ap[2][4];
        #pragma unroll
        for (int ks = 0; ks < 2; ks++)
            #pragma unroll
            for (int mg = 0; mg < 4; mg++) {
                const int row = mg * 16 + l16;
                const int bo = (ks * 64 + quad * 16) ^ ((row & 7) << 4);
                ap[ks][mg] = *(const bf16x8*)((const char*)&sps[buf][0] + row * 128 + bo);
            }

        // QK for tile n0+64 -> sps[buf^1] (register-only MFMAs + exp VALU)
        if (nxt) qk_tile(buf ^ 1);

        // PV(n0)
        #pragma unroll
        for (int ks = 0; ks < 2; ks++)
            #pragma unroll
            for (int mg = 0; mg < 4; mg++)
                #pragma unroll
                for (int ct = 0; ct < 4; ct++)
                    acc[mg][ct] = __builtin_amdgcn_mfma_f32_16x16x32_bf16(
                        ap[ks][mg], vf[ct][ks], acc[mg][ct], 0, 0, 0);

        // K prefetch for tile n0+128 (consumed by QK in next body)
        if (n0 + 128 < NPIX) {
            const size_t kb = kbase + (size_t)(n0 + 128) * ND;
            #pragma unroll
            for (int ks = 0; ks < 2; ks++) {
                kfh[ks] = *(const bf16x8*)&kh[kb + ks * 32];
                kfl[ks] = *(const bf16x8*)&kl[kb + ks * 32];
            }
        }
        // V prefetch for PV(n0+64)
        if (nxt) {
            #pragma unroll
            for (int ct = 0; ct < 4; ct++)
                #pragma unroll
                for (int ks = 0; ks < 2; ks++)
                    vf[ct][ks] = *(const bf16x8*)&vb[vbase[ct] + n0 + 64 + ks * 32];
        }

        // non-draining barrier: LDS writes visible; global prefetches in flight
        asm volatile("s_waitcnt lgkmcnt(0)\n\ts_barrier" ::: "memory");
    }

    // rowsum: reduce across quad lanes, then across the 4 nt-waves via LDS
    #pragma unroll
    for (int mg = 0; mg < 4; mg++) {
        lsum[mg] += __shfl_xor(lsum[mg], 16, 64);
        lsum[mg] += __shfl_xor(lsum[mg], 32, 64);
    }
    if (quad == 0) {
        #pragma unroll
        for (int mg = 0; mg < 4; mg++) red[w][mg * 16 + l16] = lsum[mg];
    }
    __syncthreads();
    if (t < 64)
        ivl[t] = 1.f / (red[0][t] + red[1][t] + red[2][t] + red[3][t]);
    __syncthreads();

    // epilogue: out = acc/l + x; D rows m = mg*16+quad*4+r, col c = l16
    #pragma unroll
    for (int mg = 0; mg < 4; mg++) {
        const int mrow = mg * 16 + quad * 4;
        const float4 il4 = *(const float4*)&ivl[mrow];
        const int m = m0 + mrow;
        #pragma unroll
        for (int ct = 0; ct < 4; ct++) {
            const int c = 64 * w + ct * 16 + l16;
            const size_t base = ((size_t)b * NC + c) * NPIX + m;
            const float4 xv = *(const float4*)&x[base];
            const f32x4 a = acc[mg][ct];
            float4 o;
            o.x = fmaf(a[0], il4.x, xv.x);
            o.y = fmaf(a[1], il4.y, xv.y);
            o.z = fmaf(a[2], il4.z, xv.z);
            o.w = fmaf(a[3], il4.w, xv.w);
            *(float4*)&out[base] = o;
        }
    }
}

extern "C" void kernel_launch(void* const* d_in, const int* in_sizes, int n_in,
                              void* d_out, int out_size, void* d_ws, size_t ws_size,
                              hipStream_t stream)
{
    const float* x  = (const float*)d_in[0];
    const float* Wq = (const float*)d_in[1];
    const float* bq = (const float*)d_in[2];
    const float* Wk = (const float*)d_in[3];
    const float* bk = (const float*)d_in[4];
    const float* Wv = (const float*)d_in[5];
    const float* bv = (const float*)d_in[6];
    float* outp = (float*)d_out;

    const size_t XT = (size_t)NB * NPIX * 256;   // 8,388,608
    const size_t QK = (size_t)NB * NPIX * ND;    // 2,097,152
    ushort* xt_h = (ushort*)d_ws;
    ushort* xt_l = xt_h + XT;
    ushort* v_b  = xt_l;              // alias: conv_v (after conv_split) overwrites xt_l
    ushort* q_h  = xt_l + XT;
    ushort* q_l  = q_h + QK;
    ushort* k_h  = q_l + QK;
    ushort* k_l  = k_h + QK;
    ushort* wtq_h = k_l + QK;         // 9*64*256 = 147456 each
    ushort* wtq_l = wtq_h + 147456;
    ushort* wtk_h = wtq_l + 147456;
    ushort* wtk_l = wtk_h + 147456;
    ushort* wtv_h = wtk_l + 147456;   // 9*256*256 = 589824

    dim3 blk(256);
    prep_k<<<dim3(2432), blk, 0, stream>>>(
        x, Wq, Wk, Wv, xt_h, xt_l, wtq_h, wtq_l, wtk_h, wtk_l, wtv_h);
    conv_split_k<<<dim3(256), blk, 38272, stream>>>(
        xt_h, xt_l, wtq_h, wtq_l, wtk_h, wtk_l, bq, bk, q_h, q_l, k_h, k_l);
    conv_v_k<<<dim3(512), blk, 19264, stream>>>(xt_h, wtv_h, bv, v_b);
    attn_k<<<dim3(512), blk, 0, stream>>>(q_h, q_l, k_h, k_l, v_b, x, outp);
}

// Round 12
// 406.199 us; speedup vs baseline: 1.2300x; 1.2300x over previous
//
#include <hip/hip_runtime.h>
#include <math.h>

#define NB   8
#define NC   256
#define ND   64
#define NPIX 4096

typedef short bf16x8 __attribute__((ext_vector_type(8)));   // 8 bf16 (4 VGPRs)
typedef float f32x4  __attribute__((ext_vector_type(4)));
typedef float f32x16 __attribute__((ext_vector_type(16)));

static __device__ __forceinline__ ushort f2bf(float f) {
    uint u = __float_as_uint(f);
    u += 0x7fffu + ((u >> 16) & 1u);      // round-to-nearest-even
    return (ushort)(u >> 16);
}
static __device__ __forceinline__ float bf2f(ushort h) {
    return __uint_as_float(((uint)h) << 16);
}

// ---------------------------------------------------------------------------
// prep_k: transpose_w (ids 0..383) + transpose_x (ids 384..2431) fused
// (R9-proven). transpose_x XCD-pinned by batch (R10-proven).
// NEW (R11 fix): W layout is W2[rs][ch=ci>>4][co][ci&15] — the conv's
// direct-to-register W loads become per-wave CONTIGUOUS 2KB blocks
// (R11's [rs][co][ci] layout gave 512B lane stride = 8x cache-line
// amplification, +80us). Same buffer sizes; same element values.
// Shared LDS 17408 B.
// ---------------------------------------------------------------------------
__global__ __launch_bounds__(256) void prep_k(
    const float* __restrict__ x,
    const float* __restrict__ Wq, const float* __restrict__ Wk,
    const float* __restrict__ Wv,
    ushort* __restrict__ xth, ushort* __restrict__ xtl,
    ushort* __restrict__ qh, ushort* __restrict__ ql,
    ushort* __restrict__ kh, ushort* __restrict__ kl,
    ushort* __restrict__ vh)
{
    __shared__ char shbuf[64 * 68 * 4];
    const int id = blockIdx.x;
    const int t = threadIdx.x;

    if (id < 384) {
        // ---- transpose_w body (g = id), W2 layout ----
        float* wb = (float*)shbuf;
        const int g = id;
        const float* src;
        ushort *dh, *dl;
        int co, Co, split;
        if (g < 64)       { src = Wq + (size_t)g * 2304; co = g;       Co = 64;  dh = qh; dl = ql; split = 1; }
        else if (g < 128) { src = Wk + (size_t)(g - 64) * 2304; co = g - 64; Co = 64; dh = kh; dl = kl; split = 1; }
        else              { src = Wv + (size_t)(g - 128) * 2304; co = g - 128; Co = 256; dh = vh; dl = nullptr; split = 0; }

        for (int i = t; i < 2304; i += 256) wb[i] = src[i];
        __syncthreads();
        for (int j = t; j < 2304; j += 256) {
            const int rs = j >> 8, ci = j & 255;
            const float v = wb[ci * 9 + rs];
            const ushort hv = f2bf(v);
            // W2[rs][ci>>4][co][ci&15]
            const size_t o = ((size_t)((rs * 16 + (ci >> 4)) * Co + co)) * 16 + (ci & 15);
            dh[o] = hv;
            if (split) dl[o] = f2bf(v - bf2f(hv));
        }
    } else {
        // ---- transpose_x body, XCD-pinned: b = xid&7 ----
        float (*tile)[68] = (float(*)[68])shbuf;
        const int xid = id - 384;
        const int b = xid & 7;
        const int p0 = ((xid >> 3) & 63) * 64;
        const int c0 = (xid >> 9) * 64;

        const int cl = t >> 4, p4 = (t & 15) * 4;
        #pragma unroll
        for (int i = 0; i < 4; i++) {
            const int c = cl + 16 * i;
            *(float4*)&tile[c][p4] =
                *(const float4*)&x[((size_t)(b * NC + c0 + c)) * NPIX + p0 + p4];
        }
        __syncthreads();

        const int pl = t & 63, ch = t >> 6;
        float v[16];
        #pragma unroll
        for (int j = 0; j < 16; j++) v[j] = tile[ch * 16 + j][pl];
        ushort h[16], l[16];
        #pragma unroll
        for (int j = 0; j < 16; j++) {
            h[j] = f2bf(v[j]);
            l[j] = f2bf(v[j] - bf2f(h[j]));
        }
        const size_t o = ((size_t)(b * NPIX + p0 + pl)) * 256 + c0 + ch * 16;
        *(uint4*)&xth[o]     = *(uint4*)&h[0];
        *(uint4*)&xth[o + 8] = *(uint4*)&h[8];
        *(uint4*)&xtl[o]     = *(uint4*)&l[0];
        *(uint4*)&xtl[o + 8] = *(uint4*)&l[8];
    }
}

// ---------------------------------------------------------------------------
// MFMA conv (q/k, split-bf16 3-term) v5: W direct-to-register with the
// COALESCED W2 layout. Per-lane address base(rs,ch) + l31*16 + khl*8 —
// wave covers one contiguous 2KB block (A1 co-half: +512 elems). Values
// element-identical to R0's wsp reads; per-accumulator MFMA order identical
// (pass0 then pass1) -> bit-identical output. Deletes the wsp LDS round
// trip + 2 of 4 barriers/chunk; pass0+pass1 in one 108-MFMA interval.
// grid 256 1-D (b=id&7 XCD pin), 1 block/CU, launch_bounds(256,1).
// dyn LDS 38272 B.
// ---------------------------------------------------------------------------
__global__ __launch_bounds__(256, 1) void conv_split_k(
    const ushort* __restrict__ xth, const ushort* __restrict__ xtl,
    const ushort* __restrict__ wqh, const ushort* __restrict__ wql,
    const ushort* __restrict__ wkh, const ushort* __restrict__ wkl,
    const float* __restrict__ bq, const float* __restrict__ bk,
    ushort* __restrict__ qoh, ushort* __restrict__ qol,
    ushort* __restrict__ koh, ushort* __restrict__ kol)
{
    extern __shared__ char smem[];
    ushort* xsh = (ushort*)smem;                 // [6][66][24]
    ushort* xsl = xsh + 6 * 66 * 24;             // [6][66][24]
    float*  sbias = (float*)(xsl + 6 * 66 * 24); // [64]

    const int id = blockIdx.x;
    const int b = id & 7, hq = (id >> 3) & 15, ct = id >> 7;
    const ushort* wth = ct ? wkh : wqh;
    const ushort* wtl = ct ? wkl : wql;
    const float*  bias = ct ? bk : bq;
    ushort* outh = ct ? koh : qoh;
    ushort* outl = ct ? kol : qol;

    const int t = threadIdx.x;
    const int wv = t >> 6, lane = t & 63;
    const int l31 = lane & 31, khl = lane >> 5;
    const int lanebase = l31 * 24 + khl * 8;
    const int h = hq * 4 + wv;

    if (t < 64) sbias[t] = bias[t];
    for (int i = t; i < 384; i += 256) {
        const int p = i / 192, r2 = i % 192;
        const int row = r2 / 32, e = (r2 % 32) / 16, ci = r2 & 15;
        (p ? xsl : xsh)[(row * 66 + e * 65) * 24 + ci] = 0;
    }

    // per-lane W2 offset within a (rs,ch) 1024-elem block
    const int wlane = l31 * 16 + khl * 8;

    f32x16 a00 = {0}, a01 = {0}, a10 = {0}, a11 = {0};  // [ms(co)][ns(pix)]

    for (int ch = 0; ch < 16; ch++) {
        const int ci0 = ch * 16;

        // W frags: coalesced global->reg (wave reads contiguous 2KB/load set)
        bf16x8 whA0[9], whA1[9], wlA0[9], wlA1[9];
        #pragma unroll
        for (int rs = 0; rs < 9; rs++) {
            const size_t o = (size_t)(rs * 16 + ch) * 1024 + wlane;
            whA0[rs] = *(const bf16x8*)&wth[o];
            whA1[rs] = *(const bf16x8*)&wth[o + 512];
            wlA0[rs] = *(const bf16x8*)&wtl[o];
            wlA1[rs] = *(const bf16x8*)&wtl[o + 512];
        }

        __syncthreads();   // prev chunk's x-LDS reads done
        #pragma unroll
        for (int pl2 = 0; pl2 < 2; pl2++) {
            const ushort* src = pl2 ? xtl : xth;
            ushort* dst = pl2 ? xsl : xsh;
            #pragma unroll
            for (int i = 0; i < 3; i++) {
                const int a = i * 256 + t;
                const int cih = a & 1, col = (a >> 1) & 63, row = a >> 7;
                const int hs = hq * 4 + row - 1;
                uint4 val = {0, 0, 0, 0};
                if (hs >= 0 && hs < 64)
                    val = *(const uint4*)&src[((size_t)(b * NPIX + hs * 64 + col)) * 256 + ci0 + cih * 8];
                *(uint4*)&dst[(row * 66 + 1 + col) * 24 + cih * 8] = val;
            }
        }
        __syncthreads();

        // pass0: (wh.xh) + (wh.xl) — per-acc order identical to R0
        #pragma unroll
        for (int rs = 0; rs < 9; rs++) {
            const int r = rs / 3, s = rs % 3;
            const int xo = ((wv + r) * 66 + s) * 24 + lanebase;
            bf16x8 B0h = *(const bf16x8*)&xsh[xo];
            bf16x8 B1h = *(const bf16x8*)&xsh[xo + 768];
            bf16x8 B0l = *(const bf16x8*)&xsl[xo];
            bf16x8 B1l = *(const bf16x8*)&xsl[xo + 768];
            a00 = __builtin_amdgcn_mfma_f32_32x32x16_bf16(whA0[rs], B0h, a00, 0, 0, 0);
            a01 = __builtin_amdgcn_mfma_f32_32x32x16_bf16(whA0[rs], B1h, a01, 0, 0, 0);
            a10 = __builtin_amdgcn_mfma_f32_32x32x16_bf16(whA1[rs], B0h, a10, 0, 0, 0);
            a11 = __builtin_amdgcn_mfma_f32_32x32x16_bf16(whA1[rs], B1h, a11, 0, 0, 0);
            a00 = __builtin_amdgcn_mfma_f32_32x32x16_bf16(whA0[rs], B0l, a00, 0, 0, 0);
            a01 = __builtin_amdgcn_mfma_f32_32x32x16_bf16(whA0[rs], B1l, a01, 0, 0, 0);
            a10 = __builtin_amdgcn_mfma_f32_32x32x16_bf16(whA1[rs], B0l, a10, 0, 0, 0);
            a11 = __builtin_amdgcn_mfma_f32_32x32x16_bf16(whA1[rs], B1l, a11, 0, 0, 0);
        }
        // pass1: (wl.xh) — same interval, x-LDS only read (no barrier needed)
        #pragma unroll
        for (int rs = 0; rs < 9; rs++) {
            const int r = rs / 3, s = rs % 3;
            const int xo = ((wv + r) * 66 + s) * 24 + lanebase;
            bf16x8 B0h = *(const bf16x8*)&xsh[xo];
            bf16x8 B1h = *(const bf16x8*)&xsh[xo + 768];
            a00 = __builtin_amdgcn_mfma_f32_32x32x16_bf16(wlA0[rs], B0h, a00, 0, 0, 0);
            a01 = __builtin_amdgcn_mfma_f32_32x32x16_bf16(wlA0[rs], B1h, a01, 0, 0, 0);
            a10 = __builtin_amdgcn_mfma_f32_32x32x16_bf16(wlA1[rs], B0h, a10, 0, 0, 0);
            a11 = __builtin_amdgcn_mfma_f32_32x32x16_bf16(wlA1[rs], B1h, a11, 0, 0, 0);
        }
    }

    const float4* sb4 = (const float4*)sbias;
    #pragma unroll
    for (int ms = 0; ms < 2; ms++)
        #pragma unroll
        for (int ns = 0; ns < 2; ns++) {
            const f32x16 av = ms ? (ns ? a11 : a10) : (ns ? a01 : a00);
            const int p = h * 64 + ns * 32 + l31;
            #pragma unroll
            for (int g = 0; g < 4; g++) {
                const float4 bi = sb4[ms * 8 + 2 * g + khl];
                float v0 = av[4 * g + 0] + bi.x;
                float v1 = av[4 * g + 1] + bi.y;
                float v2 = av[4 * g + 2] + bi.z;
                float v3 = av[4 * g + 3] + bi.w;
                ushort4 hv, lv;
                hv.x = f2bf(v0); lv.x = f2bf(v0 - bf2f(hv.x));
                hv.y = f2bf(v1); lv.y = f2bf(v1 - bf2f(hv.y));
                hv.z = f2bf(v2); lv.z = f2bf(v2 - bf2f(hv.z));
                hv.w = f2bf(v3); lv.w = f2bf(v3 - bf2f(hv.w));
                const size_t o = ((size_t)(b * NPIX + p)) * 64 + ms * 32 + 8 * g + 4 * khl;
                *(ushort4*)&outh[o] = hv;
                *(ushort4*)&outl[o] = lv;
            }
        }
}

// ---------------------------------------------------------------------------
// MFMA conv (v, plain bf16) v5: W direct-to-register, coalesced W2 layout
// (Co=256: block = 4096 elems per (rs,ch); B0 at (co0+l31)*16+khl*8,
// B1 = +512). Deletes wsp LDS round trip; 2 barriers/chunk.
// grid 512 1-D (b=id&7 XCD pin), 2 blocks/CU. dyn LDS 19264 B.
// ---------------------------------------------------------------------------
__global__ __launch_bounds__(256, 2) void conv_v_k(
    const ushort* __restrict__ xth, const ushort* __restrict__ wtv,
    const float* __restrict__ bv, ushort* __restrict__ vout)
{
    extern __shared__ char smem[];
    ushort* xsh = (ushort*)smem;                 // [6][66][24]
    float*  sbias = (float*)(xsh + 6 * 66 * 24); // [64]

    const int id = blockIdx.x;
    const int b = id & 7, hq = (id >> 3) & 15, co0 = (id >> 7) * 64;
    const int t = threadIdx.x;
    const int wv = t >> 6, lane = t & 63;
    const int l31 = lane & 31, khl = lane >> 5;
    const int lanebase = l31 * 24 + khl * 8;
    const int h = hq * 4 + wv;

    if (t < 64) sbias[t] = bv[co0 + t];
    for (int i = t; i < 192; i += 256) {
        const int row = i / 32, e = (i % 32) / 16, ci = i & 15;
        xsh[(row * 66 + e * 65) * 24 + ci] = 0;
    }

    const int wlane = (co0 + l31) * 16 + khl * 8;

    f32x16 a00 = {0}, a01 = {0}, a10 = {0}, a11 = {0};  // [ms(pix)][ns(co)]

    for (int ch = 0; ch < 16; ch++) {
        const int ci0 = ch * 16;

        bf16x8 wB0[9], wB1[9];
        #pragma unroll
        for (int rs = 0; rs < 9; rs++) {
            const size_t o = (size_t)(rs * 16 + ch) * 4096 + wlane;
            wB0[rs] = *(const bf16x8*)&wtv[o];
            wB1[rs] = *(const bf16x8*)&wtv[o + 512];
        }

        __syncthreads();
        #pragma unroll
        for (int i = 0; i < 3; i++) {
            const int a = i * 256 + t;
            const int cih = a & 1, col = (a >> 1) & 63, row = a >> 7;
            const int hs = hq * 4 + row - 1;
            uint4 val = {0, 0, 0, 0};
            if (hs >= 0 && hs < 64)
                val = *(const uint4*)&xth[((size_t)(b * NPIX + hs * 64 + col)) * 256 + ci0 + cih * 8];
            *(uint4*)&xsh[(row * 66 + 1 + col) * 24 + cih * 8] = val;
        }
        __syncthreads();

        #pragma unroll
        for (int rs = 0; rs < 9; rs++) {
            const int r = rs / 3, s = rs % 3;
            const int xo = ((wv + r) * 66 + s) * 24 + lanebase;
            bf16x8 A0 = *(const bf16x8*)&xsh[xo];
            bf16x8 A1 = *(const bf16x8*)&xsh[xo + 768];
            a00 = __builtin_amdgcn_mfma_f32_32x32x16_bf16(A0, wB0[rs], a00, 0, 0, 0);
            a01 = __builtin_amdgcn_mfma_f32_32x32x16_bf16(A0, wB1[rs], a01, 0, 0, 0);
            a10 = __builtin_amdgcn_mfma_f32_32x32x16_bf16(A1, wB0[rs], a10, 0, 0, 0);
            a11 = __builtin_amdgcn_mfma_f32_32x32x16_bf16(A1, wB1[rs], a11, 0, 0, 0);
        }
    }

    #pragma unroll
    for (int ns = 0; ns < 2; ns++) {
        const int co = co0 + ns * 32 + l31;
        const float bi = sbias[ns * 32 + l31];
        #pragma unroll
        for (int ms = 0; ms < 2; ms++) {
            const f32x16 av = ms ? (ns ? a11 : a10) : (ns ? a01 : a00);
            #pragma unroll
            for (int g = 0; g < 4; g++) {
                const int p = h * 64 + ms * 32 + 8 * g + 4 * khl;
                ushort4 ov;
                ov.x = f2bf(av[4 * g + 0] + bi);
                ov.y = f2bf(av[4 * g + 1] + bi);
                ov.z = f2bf(av[4 * g + 2] + bi);
                ov.w = f2bf(av[4 * g + 3] + bi);
                *(ushort4*)&vout[((size_t)(b * NC + co)) * NPIX + p] = ov;
            }
        }
    }
}

// ---------------------------------------------------------------------------
// MFMA flash attention v7 (R3/R9/R10, session best): pipeline-skewed, ONE
// lgkm-only barrier per iter, K/V register prefetch, P buffer 128B rows +
// XOR swizzle byte^=(row&7)<<4 both sides. Bit-identical numerics to v4.
// grid 512 1-D (b = id&7 -> XCD pin), block 256, LDS ~17.7 KB.
// ---------------------------------------------------------------------------
__global__ __launch_bounds__(256, 2) void attn_k(
    const ushort* __restrict__ qh, const ushort* __restrict__ ql,
    const ushort* __restrict__ kh, const ushort* __restrict__ kl,
    const ushort* __restrict__ vb, const float* __restrict__ x,
    float* __restrict__ out)
{
    const int id = blockIdx.x;
    const int b  = id & 7;
    const int m0 = (id >> 3) * 64;
    const int t  = threadIdx.x;
    const int w  = t >> 6;
    const int lane = t & 63;
    const int quad = lane >> 4;
    const int l16  = lane & 15;

    __shared__ ushort sps[2][64 * 64];   // P double buffer, 128B rows, swizzled
    __shared__ float  red[4][64];
    __shared__ float  ivl[64];

    // hoisted Q B-frags: B[col=m=l16][k=d]
    bf16x8 aqh[4][2], aql[4][2];
    #pragma unroll
    for (int mg = 0; mg < 4; mg++)
        #pragma unroll
        for (int ks = 0; ks < 2; ks++) {
            const size_t g = ((size_t)b * NPIX + m0 + mg * 16 + l16) * ND + ks * 32 + quad * 8;
            aqh[mg][ks] = *(const bf16x8*)&qh[g];
            aql[mg][ks] = *(const bf16x8*)&ql[g];
        }

    // per-wave base offsets
    const size_t kbase = ((size_t)b * NPIX + 16 * w + l16) * ND + quad * 8;   // + n0*ND + ks*32
    size_t vbase[4];
    #pragma unroll
    for (int ct = 0; ct < 4; ct++)
        vbase[ct] = ((size_t)b * NC + 64 * w + ct * 16 + l16) * NPIX + quad * 8;  // + n0 + ks*32

    // preload K/V frags for n0 = 0
    bf16x8 kfh[2], kfl[2], vf[4][2];
    #pragma unroll
    for (int ks = 0; ks < 2; ks++) {
        kfh[ks] = *(const bf16x8*)&kh[kbase + ks * 32];
        kfl[ks] = *(const bf16x8*)&kl[kbase + ks * 32];
    }
    #pragma unroll
    for (int ct = 0; ct < 4; ct++)
        #pragma unroll
        for (int ks = 0; ks < 2; ks++)
            vf[ct][ks] = *(const bf16x8*)&vb[vbase[ct] + ks * 32];

    f32x4 acc[4][4];
    #pragma unroll
    for (int i = 0; i < 4; i++)
        #pragma unroll
        for (int j = 0; j < 4; j++) acc[i][j] = (f32x4){0.f, 0.f, 0.f, 0.f};
    float lsum[4] = {0.f, 0.f, 0.f, 0.f};

    // QK tile: S^T = K.Q^T (kf regs hold this tile's K), exp, pack -> sps[obuf]
    auto qk_tile = [&](int obuf) {
        #pragma unroll
        for (int mg = 0; mg < 4; mg++) {
            f32x4 s = {0.f, 0.f, 0.f, 0.f};
            #pragma unroll
            for (int ks = 0; ks < 2; ks++) {
                s = __builtin_amdgcn_mfma_f32_16x16x32_bf16(kfh[ks], aqh[mg][ks], s, 0, 0, 0);
                s = __builtin_amdgcn_mfma_f32_16x16x32_bf16(kfl[ks], aqh[mg][ks], s, 0, 0, 0);
                s = __builtin_amdgcn_mfma_f32_16x16x32_bf16(kfh[ks], aql[mg][ks], s, 0, 0, 0);
            }
            const ushort p0 = f2bf(__expf(s[0] - 30.f));
            const ushort p1 = f2bf(__expf(s[1] - 30.f));
            const ushort p2 = f2bf(__expf(s[2] - 30.f));
            const ushort p3 = f2bf(__expf(s[3] - 30.f));
            lsum[mg] += (bf2f(p0) + bf2f(p1)) + (bf2f(p2) + bf2f(p3));
            uint2 pk;
            pk.x = (uint)p0 | ((uint)p1 << 16);
            pk.y = (uint)p2 | ((uint)p3 << 16);
            const int row = mg * 16 + l16;
            const int bo = (32 * w + quad * 8) ^ ((row & 7) << 4);
            *(uint2*)((char*)&sps[obuf][0] + row * 128 + bo) = pk;
        }
    };

    // prologue: QK(0) -> sps[0]; prefetch K(64); barrier
    qk_tile(0);
    {
        const size_t kb = kbase + (size_t)64 * ND;
        #pragma unroll
        for (int ks = 0; ks < 2; ks++) {
            kfh[ks] = *(const bf16x8*)&kh[kb + ks * 32];
            kfl[ks] = *(const bf16x8*)&kl[kb + ks * 32];
        }
    }
    asm volatile("s_waitcnt lgkmcnt(0)\n\ts_barrier" ::: "memory");

    for (int n0 = 0; n0 < NPIX; n0 += 64) {
        const int buf = (n0 >> 6) & 1;
        const bool nxt = (n0 + 64) < NPIX;

        // issue P reads for PV(n0) first (latency hides under QK MFMAs)
        bf16x8 ap[2][4];
        #pragma unroll
        for (int ks = 0; ks < 2; ks++)
            #pragma unroll
            for (int mg = 0; mg < 4; mg++) {
                const int row = mg * 16 + l16;
                const int bo = (ks * 64 + quad * 16) ^ ((row & 7) << 4);
                ap[ks][mg] = *(const bf16x8*)((const char*)&sps[buf][0] + row * 128 + bo);
            }

        // QK for tile n0+64 -> sps[buf^1] (register-only MFMAs + exp VALU)
        if (nxt) qk_tile(buf ^ 1);

        // PV(n0)
        #pragma unroll
        for (int ks = 0; ks < 2; ks++)
            #pragma unroll
            for (int mg = 0; mg < 4; mg++)
                #pragma unroll
                for (int ct = 0; ct < 4; ct++)
                    acc[mg][ct] = __builtin_amdgcn_mfma_f32_16x16x32_bf16(
                        ap[ks][mg], vf[ct][ks], acc[mg][ct], 0, 0, 0);

        // K prefetch for tile n0+128 (consumed by QK in next body)
        if (n0 + 128 < NPIX) {
            const size_t kb = kbase + (size_t)(n0 + 128) * ND;
            #pragma unroll
            for (int ks = 0; ks < 2; ks++) {
                kfh[ks] = *(const bf16x8*)&kh[kb + ks * 32];
                kfl[ks] = *(const bf16x8*)&kl[kb + ks * 32];
            }
        }
        // V prefetch for PV(n0+64)
        if (nxt) {
            #pragma unroll
            for (int ct = 0; ct < 4; ct++)
                #pragma unroll
                for (int ks = 0; ks < 2; ks++)
                    vf[ct][ks] = *(const bf16x8*)&vb[vbase[ct] + n0 + 64 + ks * 32];
        }

        // non-draining barrier: LDS writes visible; global prefetches in flight
        asm volatile("s_waitcnt lgkmcnt(0)\n\ts_barrier" ::: "memory");
    }

    // rowsum: reduce across quad lanes, then across the 4 nt-waves via LDS
    #pragma unroll
    for (int mg = 0; mg < 4; mg++) {
        lsum[mg] += __shfl_xor(lsum[mg], 16, 64);
        lsum[mg] += __shfl_xor(lsum[mg], 32, 64);
    }
    if (quad == 0) {
        #pragma unroll
        for (int mg = 0; mg < 4; mg++) red[w][mg * 16 + l16] = lsum[mg];
    }
    __syncthreads();
    if (t < 64)
        ivl[t] = 1.f / (red[0][t] + red[1][t] + red[2][t] + red[3][t]);
    __syncthreads();

    // epilogue: out = acc/l + x; D rows m = mg*16+quad*4+r, col c = l16
    #pragma unroll
    for (int mg = 0; mg < 4; mg++) {
        const int mrow = mg * 16 + quad * 4;
        const float4 il4 = *(const float4*)&ivl[mrow];
        const int m = m0 + mrow;
        #pragma unroll
        for (int ct = 0; ct < 4; ct++) {
            const int c = 64 * w + ct * 16 + l16;
            const size_t base = ((size_t)b * NC + c) * NPIX + m;
            const float4 xv = *(const float4*)&x[base];
            const f32x4 a = acc[mg][ct];
            float4 o;
            o.x = fmaf(a[0], il4.x, xv.x);
            o.y = fmaf(a[1], il4.y, xv.y);
            o.z = fmaf(a[2], il4.z, xv.z);
            o.w = fmaf(a[3], il4.w, xv.w);
            *(float4*)&out[base] = o;
        }
    }
}

extern "C" void kernel_launch(void* const* d_in, const int* in_sizes, int n_in,
                              void* d_out, int out_size, void* d_ws, size_t ws_size,
                              hipStream_t stream)
{
    const float* x  = (const float*)d_in[0];
    const float* Wq = (const float*)d_in[1];
    const float* bq = (const float*)d_in[2];
    const float* Wk = (const float*)d_in[3];
    const float* bk = (const float*)d_in[4];
    const float* Wv = (const float*)d_in[5];
    const float* bv = (const float*)d_in[6];
    float* outp = (float*)d_out;

    const size_t XT = (size_t)NB * NPIX * 256;   // 8,388,608
    const size_t QK = (size_t)NB * NPIX * ND;    // 2,097,152
    ushort* xt_h = (ushort*)d_ws;
    ushort* xt_l = xt_h + XT;
    ushort* v_b  = xt_l;              // alias: conv_v (after conv_split) overwrites xt_l
    ushort* q_h  = xt_l + XT;
    ushort* q_l  = q_h + QK;
    ushort* k_h  = q_l + QK;
    ushort* k_l  = k_h + QK;
    ushort* wtq_h = k_l + QK;         // 9*64*256 = 147456 each (W2 layout)
    ushort* wtq_l = wtq_h + 147456;
    ushort* wtk_h = wtq_l + 147456;
    ushort* wtk_l = wtk_h + 147456;
    ushort* wtv_h = wtk_l + 147456;   // 9*256*256 = 589824 (W2 layout)

    dim3 blk(256);
    prep_k<<<dim3(2432), blk, 0, stream>>>(
        x, Wq, Wk, Wv, xt_h, xt_l, wtq_h, wtq_l, wtk_h, wtk_l, wtv_h);
    conv_split_k<<<dim3(256), blk, 38272, stream>>>(
        xt_h, xt_l, wtq_h, wtq_l, wtk_h, wtk_l, bq, bk, q_h, q_l, k_h, k_l);
    conv_v_k<<<dim3(512), blk, 19264, stream>>>(xt_h, wtv_h, bv, v_b);
    attn_k<<<dim3(512), blk, 0, stream>>>(q_h, q_l, k_h, k_l, v_b, x, outp);
}

// Round 13
// 382.886 us; speedup vs baseline: 1.3049x; 1.0609x over previous
//
#include <hip/hip_runtime.h>
#include <math.h>

#define NB   8
#define NC   256
#define ND   64
#define NPIX 4096

typedef short bf16x8 __attribute__((ext_vector_type(8)));   // 8 bf16 (4 VGPRs)
typedef float f32x4  __attribute__((ext_vector_type(4)));
typedef float f32x16 __attribute__((ext_vector_type(16)));

static __device__ __forceinline__ ushort f2bf(float f) {
    uint u = __float_as_uint(f);
    u += 0x7fffu + ((u >> 16) & 1u);      // round-to-nearest-even
    return (ushort)(u >> 16);
}
static __device__ __forceinline__ float bf2f(ushort h) {
    return __uint_as_float(((uint)h) << 16);
}

// ---------------------------------------------------------------------------
// prep_k: transpose_w (ids 0..383) + transpose_x (ids 384..2431) fused
// (R9-proven). transpose_x XCD-pinned by batch (R10-proven). W2 layout
// W2[rs][ci>>4][co][ci&15] for coalesced conv W loads (R12-proven, -13us).
// Shared LDS 17408 B.
// ---------------------------------------------------------------------------
__global__ __launch_bounds__(256) void prep_k(
    const float* __restrict__ x,
    const float* __restrict__ Wq, const float* __restrict__ Wk,
    const float* __restrict__ Wv,
    ushort* __restrict__ xth, ushort* __restrict__ xtl,
    ushort* __restrict__ qh, ushort* __restrict__ ql,
    ushort* __restrict__ kh, ushort* __restrict__ kl,
    ushort* __restrict__ vh)
{
    __shared__ char shbuf[64 * 68 * 4];
    const int id = blockIdx.x;
    const int t = threadIdx.x;

    if (id < 384) {
        // ---- transpose_w body (g = id), W2 layout ----
        float* wb = (float*)shbuf;
        const int g = id;
        const float* src;
        ushort *dh, *dl;
        int co, Co, split;
        if (g < 64)       { src = Wq + (size_t)g * 2304; co = g;       Co = 64;  dh = qh; dl = ql; split = 1; }
        else if (g < 128) { src = Wk + (size_t)(g - 64) * 2304; co = g - 64; Co = 64; dh = kh; dl = kl; split = 1; }
        else              { src = Wv + (size_t)(g - 128) * 2304; co = g - 128; Co = 256; dh = vh; dl = nullptr; split = 0; }

        for (int i = t; i < 2304; i += 256) wb[i] = src[i];
        __syncthreads();
        for (int j = t; j < 2304; j += 256) {
            const int rs = j >> 8, ci = j & 255;
            const float v = wb[ci * 9 + rs];
            const ushort hv = f2bf(v);
            // W2[rs][ci>>4][co][ci&15]
            const size_t o = ((size_t)((rs * 16 + (ci >> 4)) * Co + co)) * 16 + (ci & 15);
            dh[o] = hv;
            if (split) dl[o] = f2bf(v - bf2f(hv));
        }
    } else {
        // ---- transpose_x body, XCD-pinned: b = xid&7 ----
        float (*tile)[68] = (float(*)[68])shbuf;
        const int xid = id - 384;
        const int b = xid & 7;
        const int p0 = ((xid >> 3) & 63) * 64;
        const int c0 = (xid >> 9) * 64;

        const int cl = t >> 4, p4 = (t & 15) * 4;
        #pragma unroll
        for (int i = 0; i < 4; i++) {
            const int c = cl + 16 * i;
            *(float4*)&tile[c][p4] =
                *(const float4*)&x[((size_t)(b * NC + c0 + c)) * NPIX + p0 + p4];
        }
        __syncthreads();

        const int pl = t & 63, ch = t >> 6;
        float v[16];
        #pragma unroll
        for (int j = 0; j < 16; j++) v[j] = tile[ch * 16 + j][pl];
        ushort h[16], l[16];
        #pragma unroll
        for (int j = 0; j < 16; j++) {
            h[j] = f2bf(v[j]);
            l[j] = f2bf(v[j] - bf2f(h[j]));
        }
        const size_t o = ((size_t)(b * NPIX + p0 + pl)) * 256 + c0 + ch * 16;
        *(uint4*)&xth[o]     = *(uint4*)&h[0];
        *(uint4*)&xth[o + 8] = *(uint4*)&h[8];
        *(uint4*)&xtl[o]     = *(uint4*)&l[0];
        *(uint4*)&xtl[o + 8] = *(uint4*)&l[8];
    }
}

// ---------------------------------------------------------------------------
// MFMA conv (q/k, split-bf16 3-term) v6: R12's W-direct-to-reg (coalesced W2)
// + ROLLING PREFETCH + x LDS DOUBLE-BUFFER.
// Per chunk: [issue x(ch+1)->regs] [pass0: 72 MFMA] [refill whA(ch+1): dead]
// [pass1: 36 MFMA] [refill wlA(ch+1): dead] [ds_write x->buf^1] [ONE lgkm
// barrier]. x-load latency hides under the 108-MFMA interval (attn_k's proven
// K/V-prefetch pattern); barriers 2->1/chunk (dbuf: lgkmcnt(0) retires each
// wave's reads of buf AND writes of buf^1 before s_barrier). MFMA operand
// values + per-acc order identical to R12 -> bit-identical output.
// grid 256 1-D (b=id&7 XCD pin), 1 block/CU, launch_bounds(256,1).
// dyn LDS 76288 B (2buf x 2plane x [6][66][24] + bias).
// ---------------------------------------------------------------------------
__global__ __launch_bounds__(256, 1) void conv_split_k(
    const ushort* __restrict__ xth, const ushort* __restrict__ xtl,
    const ushort* __restrict__ wqh, const ushort* __restrict__ wql,
    const ushort* __restrict__ wkh, const ushort* __restrict__ wkl,
    const float* __restrict__ bq, const float* __restrict__ bk,
    ushort* __restrict__ qoh, ushort* __restrict__ qol,
    ushort* __restrict__ koh, ushort* __restrict__ kol)
{
    extern __shared__ char smem[];
    ushort* xbase = (ushort*)smem;               // [2 buf][2 plane][6][66][24]
    float*  sbias = (float*)(xbase + 38016);     // [64]

    const int id = blockIdx.x;
    const int b = id & 7, hq = (id >> 3) & 15, ct = id >> 7;
    const ushort* wth = ct ? wkh : wqh;
    const ushort* wtl = ct ? wkl : wql;
    const float*  bias = ct ? bk : bq;
    ushort* outh = ct ? koh : qoh;
    ushort* outl = ct ? kol : qol;

    const int t = threadIdx.x;
    const int wv = t >> 6, lane = t & 63;
    const int l31 = lane & 31, khl = lane >> 5;
    const int lanebase = l31 * 24 + khl * 8;
    const int h = hq * 4 + wv;

    if (t < 64) sbias[t] = bias[t];
    // zero col-halo (cols 0 and 65) for both planes of both buffers
    for (int i = t; i < 768; i += 256) {
        const int pl = i / 192, r2 = i % 192;
        const int row = r2 / 32, e = (r2 % 32) / 16, ci = r2 & 15;
        xbase[pl * 9504 + (row * 66 + e * 65) * 24 + ci] = 0;
    }

    // hoisted per-thread x staging map (3 loads/plane)
    int xrow[3], xcol[3], xcih[3];
    bool xval[3];
    #pragma unroll
    for (int i = 0; i < 3; i++) {
        const int a = i * 256 + t;
        xcih[i] = a & 1; xcol[i] = (a >> 1) & 63; xrow[i] = a >> 7;
        const int hs = hq * 4 + xrow[i] - 1;
        xval[i] = (hs >= 0 && hs < 64);
    }
    const int wlane = l31 * 16 + khl * 8;   // per-lane W2 offset in (rs,ch) block

    f32x16 a00 = {0}, a01 = {0}, a10 = {0}, a11 = {0};  // [ms(co)][ns(pix)]

    // loop-carried W frags
    bf16x8 whA0[9], whA1[9], wlA0[9], wlA1[9];

    // ---- prologue: stage x(0) -> buf0; load W(0) ----
    {
        #pragma unroll
        for (int i = 0; i < 3; i++) {
            const int hs = hq * 4 + xrow[i] - 1;
            uint4 vh4 = {0,0,0,0}, vl4 = {0,0,0,0};
            if (xval[i]) {
                const size_t g = ((size_t)(b * NPIX + hs * 64 + xcol[i])) * 256 + xcih[i] * 8;
                vh4 = *(const uint4*)&xth[g];
                vl4 = *(const uint4*)&xtl[g];
            }
            const int o = (xrow[i] * 66 + 1 + xcol[i]) * 24 + xcih[i] * 8;
            *(uint4*)&xbase[o]        = vh4;
            *(uint4*)&xbase[9504 + o] = vl4;
        }
        #pragma unroll
        for (int rs = 0; rs < 9; rs++) {
            const size_t o = (size_t)(rs * 16) * 1024 + wlane;
            whA0[rs] = *(const bf16x8*)&wth[o];
            whA1[rs] = *(const bf16x8*)&wth[o + 512];
            wlA0[rs] = *(const bf16x8*)&wtl[o];
            wlA1[rs] = *(const bf16x8*)&wtl[o + 512];
        }
    }
    asm volatile("s_waitcnt lgkmcnt(0)\n\ts_barrier" ::: "memory");

    for (int ch = 0; ch < 16; ch++) {
        const int cur = ch & 1;
        ushort* xsh = xbase + cur * 19008;
        ushort* xsl = xsh + 9504;
        const bool nxt = ch < 15;
        const int ci0n = (ch + 1) * 16;

        // issue x(ch+1) loads -> regs (latency hides under 108 MFMAs below)
        uint4 xrh[3], xrl[3];
        if (nxt) {
            #pragma unroll
            for (int i = 0; i < 3; i++) {
                const int hs = hq * 4 + xrow[i] - 1;
                xrh[i] = (uint4){0,0,0,0}; xrl[i] = (uint4){0,0,0,0};
                if (xval[i]) {
                    const size_t g = ((size_t)(b * NPIX + hs * 64 + xcol[i])) * 256 + ci0n + xcih[i] * 8;
                    xrh[i] = *(const uint4*)&xth[g];
                    xrl[i] = *(const uint4*)&xtl[g];
                }
            }
        }

        // pass0: (wh.xh) + (wh.xl) — per-acc order identical to R12
        #pragma unroll
        for (int rs = 0; rs < 9; rs++) {
            const int r = rs / 3, s = rs % 3;
            const int xo = ((wv + r) * 66 + s) * 24 + lanebase;
            bf16x8 B0h = *(const bf16x8*)&xsh[xo];
            bf16x8 B1h = *(const bf16x8*)&xsh[xo + 768];
            bf16x8 B0l = *(const bf16x8*)&xsl[xo];
            bf16x8 B1l = *(const bf16x8*)&xsl[xo + 768];
            a00 = __builtin_amdgcn_mfma_f32_32x32x16_bf16(whA0[rs], B0h, a00, 0, 0, 0);
            a01 = __builtin_amdgcn_mfma_f32_32x32x16_bf16(whA0[rs], B1h, a01, 0, 0, 0);
            a10 = __builtin_amdgcn_mfma_f32_32x32x16_bf16(whA1[rs], B0h, a10, 0, 0, 0);
            a11 = __builtin_amdgcn_mfma_f32_32x32x16_bf16(whA1[rs], B1h, a11, 0, 0, 0);
            a00 = __builtin_amdgcn_mfma_f32_32x32x16_bf16(whA0[rs], B0l, a00, 0, 0, 0);
            a01 = __builtin_amdgcn_mfma_f32_32x32x16_bf16(whA0[rs], B1l, a01, 0, 0, 0);
            a10 = __builtin_amdgcn_mfma_f32_32x32x16_bf16(whA1[rs], B0l, a10, 0, 0, 0);
            a11 = __builtin_amdgcn_mfma_f32_32x32x16_bf16(whA1[rs], B1l, a11, 0, 0, 0);
        }
        // whA dead -> refill for ch+1 (hides under pass1)
        if (nxt) {
            #pragma unroll
            for (int rs = 0; rs < 9; rs++) {
                const size_t o = (size_t)(rs * 16 + ch + 1) * 1024 + wlane;
                whA0[rs] = *(const bf16x8*)&wth[o];
                whA1[rs] = *(const bf16x8*)&wth[o + 512];
            }
        }
        // pass1: (wl.xh)
        #pragma unroll
        for (int rs = 0; rs < 9; rs++) {
            const int r = rs / 3, s = rs % 3;
            const int xo = ((wv + r) * 66 + s) * 24 + lanebase;
            bf16x8 B0h = *(const bf16x8*)&xsh[xo];
            bf16x8 B1h = *(const bf16x8*)&xsh[xo + 768];
            a00 = __builtin_amdgcn_mfma_f32_32x32x16_bf16(wlA0[rs], B0h, a00, 0, 0, 0);
            a01 = __builtin_amdgcn_mfma_f32_32x32x16_bf16(wlA0[rs], B1h, a01, 0, 0, 0);
            a10 = __builtin_amdgcn_mfma_f32_32x32x16_bf16(wlA1[rs], B0h, a10, 0, 0, 0);
            a11 = __builtin_amdgcn_mfma_f32_32x32x16_bf16(wlA1[rs], B1h, a11, 0, 0, 0);
        }
        if (nxt) {
            // wlA dead -> refill for ch+1 (hides under ds_write + barrier)
            #pragma unroll
            for (int rs = 0; rs < 9; rs++) {
                const size_t o = (size_t)(rs * 16 + ch + 1) * 1024 + wlane;
                wlA0[rs] = *(const bf16x8*)&wtl[o];
                wlA1[rs] = *(const bf16x8*)&wtl[o + 512];
            }
            // write x(ch+1) to the other buffer (vmcnt waits only for xr)
            ushort* dsh = xbase + (cur ^ 1) * 19008;
            ushort* dsl = dsh + 9504;
            #pragma unroll
            for (int i = 0; i < 3; i++) {
                const int o = (xrow[i] * 66 + 1 + xcol[i]) * 24 + xcih[i] * 8;
                *(uint4*)&dsh[o] = xrh[i];
                *(uint4*)&dsl[o] = xrl[i];
            }
            // ONE barrier: my reads of buf + my writes of buf^1 retired
            asm volatile("s_waitcnt lgkmcnt(0)\n\ts_barrier" ::: "memory");
        }
    }

    const float4* sb4 = (const float4*)sbias;
    #pragma unroll
    for (int ms = 0; ms < 2; ms++)
        #pragma unroll
        for (int ns = 0; ns < 2; ns++) {
            const f32x16 av = ms ? (ns ? a11 : a10) : (ns ? a01 : a00);
            const int p = h * 64 + ns * 32 + l31;
            #pragma unroll
            for (int g = 0; g < 4; g++) {
                const float4 bi = sb4[ms * 8 + 2 * g + khl];
                float v0 = av[4 * g + 0] + bi.x;
                float v1 = av[4 * g + 1] + bi.y;
                float v2 = av[4 * g + 2] + bi.z;
                float v3 = av[4 * g + 3] + bi.w;
                ushort4 hv, lv;
                hv.x = f2bf(v0); lv.x = f2bf(v0 - bf2f(hv.x));
                hv.y = f2bf(v1); lv.y = f2bf(v1 - bf2f(hv.y));
                hv.z = f2bf(v2); lv.z = f2bf(v2 - bf2f(hv.z));
                hv.w = f2bf(v3); lv.w = f2bf(v3 - bf2f(hv.w));
                const size_t o = ((size_t)(b * NPIX + p)) * 64 + ms * 32 + 8 * g + 4 * khl;
                *(ushort4*)&outh[o] = hv;
                *(ushort4*)&outl[o] = lv;
            }
        }
}

// ---------------------------------------------------------------------------
// MFMA conv (v, plain bf16) v6: W direct-to-reg (coalesced W2) + rolling x
// prefetch + x LDS double-buffer, ONE lgkm barrier/chunk. wB refilled after
// the MFMA interval (dead regs). grid 512 1-D (b=id&7 XCD pin), 2 blocks/CU.
// dyn LDS 38272 B.
// ---------------------------------------------------------------------------
__global__ __launch_bounds__(256, 2) void conv_v_k(
    const ushort* __restrict__ xth, const ushort* __restrict__ wtv,
    const float* __restrict__ bv, ushort* __restrict__ vout)
{
    extern __shared__ char smem[];
    ushort* xbase = (ushort*)smem;               // [2 buf][6][66][24]
    float*  sbias = (float*)(xbase + 19008);     // [64]

    const int id = blockIdx.x;
    const int b = id & 7, hq = (id >> 3) & 15, co0 = (id >> 7) * 64;
    const int t = threadIdx.x;
    const int wv = t >> 6, lane = t & 63;
    const int l31 = lane & 31, khl = lane >> 5;
    const int lanebase = l31 * 24 + khl * 8;
    const int h = hq * 4 + wv;

    if (t < 64) sbias[t] = bv[co0 + t];
    for (int i = t; i < 384; i += 256) {
        const int pl = i / 192, r2 = i % 192;
        const int row = r2 / 32, e = (r2 % 32) / 16, ci = r2 & 15;
        xbase[pl * 9504 + (row * 66 + e * 65) * 24 + ci] = 0;
    }

    int xrow[3], xcol[3], xcih[3];
    bool xval[3];
    #pragma unroll
    for (int i = 0; i < 3; i++) {
        const int a = i * 256 + t;
        xcih[i] = a & 1; xcol[i] = (a >> 1) & 63; xrow[i] = a >> 7;
        const int hs = hq * 4 + xrow[i] - 1;
        xval[i] = (hs >= 0 && hs < 64);
    }
    const int wlane = (co0 + l31) * 16 + khl * 8;

    f32x16 a00 = {0}, a01 = {0}, a10 = {0}, a11 = {0};  // [ms(pix)][ns(co)]

    bf16x8 wB0[9], wB1[9];

    // ---- prologue: stage x(0) -> buf0; load W(0) ----
    {
        #pragma unroll
        for (int i = 0; i < 3; i++) {
            const int hs = hq * 4 + xrow[i] - 1;
            uint4 v4 = {0,0,0,0};
            if (xval[i])
                v4 = *(const uint4*)&xth[((size_t)(b * NPIX + hs * 64 + xcol[i])) * 256 + xcih[i] * 8];
            *(uint4*)&xbase[(xrow[i] * 66 + 1 + xcol[i]) * 24 + xcih[i] * 8] = v4;
        }
        #pragma unroll
        for (int rs = 0; rs < 9; rs++) {
            const size_t o = (size_t)(rs * 16) * 4096 + wlane;
            wB0[rs] = *(const bf16x8*)&wtv[o];
            wB1[rs] = *(const bf16x8*)&wtv[o + 512];
        }
    }
    asm volatile("s_waitcnt lgkmcnt(0)\n\ts_barrier" ::: "memory");

    for (int ch = 0; ch < 16; ch++) {
        const int cur = ch & 1;
        ushort* xsh = xbase + cur * 9504;
        const bool nxt = ch < 15;
        const int ci0n = (ch + 1) * 16;

        uint4 xr[3];
        if (nxt) {
            #pragma unroll
            for (int i = 0; i < 3; i++) {
                const int hs = hq * 4 + xrow[i] - 1;
                xr[i] = (uint4){0,0,0,0};
                if (xval[i])
                    xr[i] = *(const uint4*)&xth[((size_t)(b * NPIX + hs * 64 + xcol[i])) * 256 + ci0n + xcih[i] * 8];
            }
        }

        #pragma unroll
        for (int rs = 0; rs < 9; rs++) {
            const int r = rs / 3, s = rs % 3;
            const int xo = ((wv + r) * 66 + s) * 24 + lanebase;
            bf16x8 A0 = *(const bf16x8*)&xsh[xo];
            bf16x8 A1 = *(const bf16x8*)&xsh[xo + 768];
            a00 = __builtin_amdgcn_mfma_f32_32x32x16_bf16(A0, wB0[rs], a00, 0, 0, 0);
            a01 = __builtin_amdgcn_mfma_f32_32x32x16_bf16(A0, wB1[rs], a01, 0, 0, 0);
            a10 = __builtin_amdgcn_mfma_f32_32x32x16_bf16(A1, wB0[rs], a10, 0, 0, 0);
            a11 = __builtin_amdgcn_mfma_f32_32x32x16_bf16(A1, wB1[rs], a11, 0, 0, 0);
        }

        if (nxt) {
            // wB dead -> refill for ch+1 (hides under ds_write + barrier)
            #pragma unroll
            for (int rs = 0; rs < 9; rs++) {
                const size_t o = (size_t)(rs * 16 + ch + 1) * 4096 + wlane;
                wB0[rs] = *(const bf16x8*)&wtv[o];
                wB1[rs] = *(const bf16x8*)&wtv[o + 512];
            }
            ushort* dsh = xbase + (cur ^ 1) * 9504;
            #pragma unroll
            for (int i = 0; i < 3; i++)
                *(uint4*)&dsh[(xrow[i] * 66 + 1 + xcol[i]) * 24 + xcih[i] * 8] = xr[i];
            asm volatile("s_waitcnt lgkmcnt(0)\n\ts_barrier" ::: "memory");
        }
    }

    #pragma unroll
    for (int ns = 0; ns < 2; ns++) {
        const int co = co0 + ns * 32 + l31;
        const float bi = sbias[ns * 32 + l31];
        #pragma unroll
        for (int ms = 0; ms < 2; ms++) {
            const f32x16 av = ms ? (ns ? a11 : a10) : (ns ? a01 : a00);
            #pragma unroll
            for (int g = 0; g < 4; g++) {
                const int p = h * 64 + ms * 32 + 8 * g + 4 * khl;
                ushort4 ov;
                ov.x = f2bf(av[4 * g + 0] + bi);
                ov.y = f2bf(av[4 * g + 1] + bi);
                ov.z = f2bf(av[4 * g + 2] + bi);
                ov.w = f2bf(av[4 * g + 3] + bi);
                *(ushort4*)&vout[((size_t)(b * NC + co)) * NPIX + p] = ov;
            }
        }
    }
}

// ---------------------------------------------------------------------------
// MFMA flash attention v7 (R3/R9/R10/R12, session best): pipeline-skewed, ONE
// lgkm-only barrier per iter, K/V register prefetch, P buffer 128B rows +
// XOR swizzle byte^=(row&7)<<4 both sides. Bit-identical numerics to v4.
// grid 512 1-D (b = id&7 -> XCD pin), block 256, LDS ~17.7 KB.
// ---------------------------------------------------------------------------
__global__ __launch_bounds__(256, 2) void attn_k(
    const ushort* __restrict__ qh, const ushort* __restrict__ ql,
    const ushort* __restrict__ kh, const ushort* __restrict__ kl,
    const ushort* __restrict__ vb, const float* __restrict__ x,
    float* __restrict__ out)
{
    const int id = blockIdx.x;
    const int b  = id & 7;
    const int m0 = (id >> 3) * 64;
    const int t  = threadIdx.x;
    const int w  = t >> 6;
    const int lane = t & 63;
    const int quad = lane >> 4;
    const int l16  = lane & 15;

    __shared__ ushort sps[2][64 * 64];   // P double buffer, 128B rows, swizzled
    __shared__ float  red[4][64];
    __shared__ float  ivl[64];

    // hoisted Q B-frags: B[col=m=l16][k=d]
    bf16x8 aqh[4][2], aql[4][2];
    #pragma unroll
    for (int mg = 0; mg < 4; mg++)
        #pragma unroll
        for (int ks = 0; ks < 2; ks++) {
            const size_t g = ((size_t)b * NPIX + m0 + mg * 16 + l16) * ND + ks * 32 + quad * 8;
            aqh[mg][ks] = *(const bf16x8*)&qh[g];
            aql[mg][ks] = *(const bf16x8*)&ql[g];
        }

    // per-wave base offsets
    const size_t kbase = ((size_t)b * NPIX + 16 * w + l16) * ND + quad * 8;   // + n0*ND + ks*32
    size_t vbase[4];
    #pragma unroll
    for (int ct = 0; ct < 4; ct++)
        vbase[ct] = ((size_t)b * NC + 64 * w + ct * 16 + l16) * NPIX + quad * 8;  // + n0 + ks*32

    // preload K/V frags for n0 = 0
    bf16x8 kfh[2], kfl[2], vf[4][2];
    #pragma unroll
    for (int ks = 0; ks < 2; ks++) {
        kfh[ks] = *(const bf16x8*)&kh[kbase + ks * 32];
        kfl[ks] = *(const bf16x8*)&kl[kbase + ks * 32];
    }
    #pragma unroll
    for (int ct = 0; ct < 4; ct++)
        #pragma unroll
        for (int ks = 0; ks < 2; ks++)
            vf[ct][ks] = *(const bf16x8*)&vb[vbase[ct] + ks * 32];

    f32x4 acc[4][4];
    #pragma unroll
    for (int i = 0; i < 4; i++)
        #pragma unroll
        for (int j = 0; j < 4; j++) acc[i][j] = (f32x4){0.f, 0.f, 0.f, 0.f};
    float lsum[4] = {0.f, 0.f, 0.f, 0.f};

    // QK tile: S^T = K.Q^T (kf regs hold this tile's K), exp, pack -> sps[obuf]
    auto qk_tile = [&](int obuf) {
        #pragma unroll
        for (int mg = 0; mg < 4; mg++) {
            f32x4 s = {0.f, 0.f, 0.f, 0.f};
            #pragma unroll
            for (int ks = 0; ks < 2; ks++) {
                s = __builtin_amdgcn_mfma_f32_16x16x32_bf16(kfh[ks], aqh[mg][ks], s, 0, 0, 0);
                s = __builtin_amdgcn_mfma_f32_16x16x32_bf16(kfl[ks], aqh[mg][ks], s, 0, 0, 0);
                s = __builtin_amdgcn_mfma_f32_16x16x32_bf16(kfh[ks], aql[mg][ks], s, 0, 0, 0);
            }
            const ushort p0 = f2bf(__expf(s[0] - 30.f));
            const ushort p1 = f2bf(__expf(s[1] - 30.f));
            const ushort p2 = f2bf(__expf(s[2] - 30.f));
            const ushort p3 = f2bf(__expf(s[3] - 30.f));
            lsum[mg] += (bf2f(p0) + bf2f(p1)) + (bf2f(p2) + bf2f(p3));
            uint2 pk;
            pk.x = (uint)p0 | ((uint)p1 << 16);
            pk.y = (uint)p2 | ((uint)p3 << 16);
            const int row = mg * 16 + l16;
            const int bo = (32 * w + quad * 8) ^ ((row & 7) << 4);
            *(uint2*)((char*)&sps[obuf][0] + row * 128 + bo) = pk;
        }
    };

    // prologue: QK(0) -> sps[0]; prefetch K(64); barrier
    qk_tile(0);
    {
        const size_t kb = kbase + (size_t)64 * ND;
        #pragma unroll
        for (int ks = 0; ks < 2; ks++) {
            kfh[ks] = *(const bf16x8*)&kh[kb + ks * 32];
            kfl[ks] = *(const bf16x8*)&kl[kb + ks * 32];
        }
    }
    asm volatile("s_waitcnt lgkmcnt(0)\n\ts_barrier" ::: "memory");

    for (int n0 = 0; n0 < NPIX; n0 += 64) {
        const int buf = (n0 >> 6) & 1;
        const bool nxt = (n0 + 64) < NPIX;

        // issue P reads for PV(n0) first (latency hides under QK MFMAs)
        bf16x8 ap[2][4];
        #pragma unroll
        for (int ks = 0; ks < 2; ks++)
            #pragma unroll
            for (int mg = 0; mg < 4; mg++) {
                const int row = mg * 16 + l16;
                const int bo = (ks * 64 + quad * 16) ^ ((row & 7) << 4);
                ap[ks][mg] = *(const bf16x8*)((const char*)&sps[buf][0] + row * 128 + bo);
            }

        // QK for tile n0+64 -> sps[buf^1] (register-only MFMAs + exp VALU)
        if (nxt) qk_tile(buf ^ 1);

        // PV(n0)
        #pragma unroll
        for (int ks = 0; ks < 2; ks++)
            #pragma unroll
            for (int mg = 0; mg < 4; mg++)
                #pragma unroll
                for (int ct = 0; ct < 4; ct++)
                    acc[mg][ct] = __builtin_amdgcn_mfma_f32_16x16x32_bf16(
                        ap[ks][mg], vf[ct][ks], acc[mg][ct], 0, 0, 0);

        // K prefetch for tile n0+128 (consumed by QK in next body)
        if (n0 + 128 < NPIX) {
            const size_t kb = kbase + (size_t)(n0 + 128) * ND;
            #pragma unroll
            for (int ks = 0; ks < 2; ks++) {
                kfh[ks] = *(const bf16x8*)&kh[kb + ks * 32];
                kfl[ks] = *(const bf16x8*)&kl[kb + ks * 32];
            }
        }
        // V prefetch for PV(n0+64)
        if (nxt) {
            #pragma unroll
            for (int ct = 0; ct < 4; ct++)
                #pragma unroll
                for (int ks = 0; ks < 2; ks++)
                    vf[ct][ks] = *(const bf16x8*)&vb[vbase[ct] + n0 + 64 + ks * 32];
        }

        // non-draining barrier: LDS writes visible; global prefetches in flight
        asm volatile("s_waitcnt lgkmcnt(0)\n\ts_barrier" ::: "memory");
    }

    // rowsum: reduce across quad lanes, then across the 4 nt-waves via LDS
    #pragma unroll
    for (int mg = 0; mg < 4; mg++) {
        lsum[mg] += __shfl_xor(lsum[mg], 16, 64);
        lsum[mg] += __shfl_xor(lsum[mg], 32, 64);
    }
    if (quad == 0) {
        #pragma unroll
        for (int mg = 0; mg < 4; mg++) red[w][mg * 16 + l16] = lsum[mg];
    }
    __syncthreads();
    if (t < 64)
        ivl[t] = 1.f / (red[0][t] + red[1][t] + red[2][t] + red[3][t]);
    __syncthreads();

    // epilogue: out = acc/l + x; D rows m = mg*16+quad*4+r, col c = l16
    #pragma unroll
    for (int mg = 0; mg < 4; mg++) {
        const int mrow = mg * 16 + quad * 4;
        const float4 il4 = *(const float4*)&ivl[mrow];
        const int m = m0 + mrow;
        #pragma unroll
        for (int ct = 0; ct < 4; ct++) {
            const int c = 64 * w + ct * 16 + l16;
            const size_t base = ((size_t)b * NC + c) * NPIX + m;
            const float4 xv = *(const float4*)&x[base];
            const f32x4 a = acc[mg][ct];
            float4 o;
            o.x = fmaf(a[0], il4.x, xv.x);
            o.y = fmaf(a[1], il4.y, xv.y);
            o.z = fmaf(a[2], il4.z, xv.z);
            o.w = fmaf(a[3], il4.w, xv.w);
            *(float4*)&out[base] = o;
        }
    }
}

extern "C" void kernel_launch(void* const* d_in, const int* in_sizes, int n_in,
                              void* d_out, int out_size, void* d_ws, size_t ws_size,
                              hipStream_t stream)
{
    const float* x  = (const float*)d_in[0];
    const float* Wq = (const float*)d_in[1];
    const float* bq = (const float*)d_in[2];
    const float* Wk = (const float*)d_in[3];
    const float* bk = (const float*)d_in[4];
    const float* Wv = (const float*)d_in[5];
    const float* bv = (const float*)d_in[6];
    float* outp = (float*)d_out;

    const size_t XT = (size_t)NB * NPIX * 256;   // 8,388,608
    const size_t QK = (size_t)NB * NPIX * ND;    // 2,097,152
    ushort* xt_h = (ushort*)d_ws;
    ushort* xt_l = xt_h + XT;
    ushort* v_b  = xt_l;              // alias: conv_v (after conv_split) overwrites xt_l
    ushort* q_h  = xt_l + XT;
    ushort* q_l  = q_h + QK;
    ushort* k_h  = q_l + QK;
    ushort* k_l  = k_h + QK;
    ushort* wtq_h = k_l + QK;         // 9*64*256 = 147456 each (W2 layout)
    ushort* wtq_l = wtq_h + 147456;
    ushort* wtk_h = wtq_l + 147456;
    ushort* wtk_l = wtk_h + 147456;
    ushort* wtv_h = wtk_l + 147456;   // 9*256*256 = 589824 (W2 layout)

    dim3 blk(256);
    prep_k<<<dim3(2432), blk, 0, stream>>>(
        x, Wq, Wk, Wv, xt_h, xt_l, wtq_h, wtq_l, wtk_h, wtk_l, wtv_h);
    conv_split_k<<<dim3(256), blk, 76288, stream>>>(
        xt_h, xt_l, wtq_h, wtq_l, wtk_h, wtk_l, bq, bk, q_h, q_l, k_h, k_l);
    conv_v_k<<<dim3(512), blk, 38272, stream>>>(xt_h, wtv_h, bv, v_b);
    attn_k<<<dim3(512), blk, 0, stream>>>(q_h, q_l, k_h, k_l, v_b, x, outp);
}